// Round 5
// baseline (221.994 us; speedup 1.0000x reference)
//
#include <hip/hip_runtime.h>
#include <stdint.h>
#include <stddef.h>

#define NB 8
#define NSEQ 4096
#define NC 512
#define NH 8

typedef __attribute__((ext_vector_type(4))) float f4;
typedef __attribute__((ext_vector_type(8))) short bf8;
typedef __attribute__((ext_vector_type(4))) short bf4;
typedef __attribute__((ext_vector_type(2))) unsigned int u32x2;
typedef __attribute__((ext_vector_type(4))) unsigned int u32x4;

__device__ __forceinline__ short f2bf(float f) {
  union { float f; unsigned int u; } v; v.f = f;
  unsigned int u = v.u + 0x7FFFu + ((v.u >> 16) & 1u);
  return (short)(u >> 16);
}
__device__ __forceinline__ float bf2f(short h) {
  union { unsigned int u; float f; } v;
  v.u = ((unsigned int)(unsigned short)h) << 16;
  return v.f;
}
__device__ __forceinline__ unsigned int cvtpk(float a, float b) {
  unsigned int r;
  asm("v_cvt_pk_bf16_f32 %0, %1, %2" : "=v"(r) : "v"(a), "v"(b));
  return r;
}

// K0a: Wth/Wtl[s][o][c] = split(W_s[c][o]) via 64x64 LDS transpose (coalesced both sides).
__global__ __launch_bounds__(256) void k_wt(const float* __restrict__ W0,
                                            const float* __restrict__ W1,
                                            short* __restrict__ Wth,
                                            short* __restrict__ Wtl) {
  __shared__ float t[64 * 65];
  int bid = blockIdx.x;           // [s 1][ct 3][ot 4] = 256
  int ot = bid & 15;
  int ct = (bid >> 4) & 7;
  int s = bid >> 7;
  const float* W = s ? W1 : W0;
  const float* src = W + (size_t)(ct * 64) * 1024 + ot * 64;   // [c][o]
  int tid = threadIdx.x;
  int rr = tid >> 4, c4 = (tid & 15) * 4;
#pragma unroll
  for (int p = 0; p < 4; ++p) {
    int c = p * 16 + rr;
    f4 v = *(const f4*)&src[(size_t)c * 1024 + c4];
#pragma unroll
    for (int i = 0; i < 4; ++i) t[(c4 + i) * 65 + c] = v[i];   // t[o][c]
  }
  __syncthreads();
  size_t obase = (size_t)s * 524288 + (size_t)(ot * 64) * 512 + ct * 64;
#pragma unroll
  for (int p = 0; p < 4; ++p) {
    int o = p * 16 + rr;
    bf4 vh, vl;
#pragma unroll
    for (int i = 0; i < 4; ++i) {
      float v = t[o * 65 + c4 + i];
      short h = f2bf(v);
      vh[i] = h; vl[i] = f2bf(v - bf2f(h));
    }
    *(bf4*)&Wth[obase + (size_t)o * 512 + c4] = vh;
    *(bf4*)&Wtl[obase + (size_t)o * 512 + c4] = vl;
  }
}

// K1: G32[sb] upper 64x64 tile-pairs = X^T X reading f32 x DIRECTLY (no XbT pass).
// Full-K (4096), no atomics. Per K-step: load 64n x 64c f4-coalesced, in-register
// 4x4 transpose + cvt_pk to bf16, ds_write_b64 into XOR-swizzled [c][n] LDS.
// T14 split: loads(t+1) issued before MFMA(t); cvt+write after; 1 barrier/step.
__global__ __launch_bounds__(256) void k_gram(const float* __restrict__ x0,
                                              const float* __restrict__ x1,
                                              float* __restrict__ G32) {
  __shared__ short Ab[2][64 * 64];
  __shared__ short Bb[2][64 * 64];
  int bid = blockIdx.x;            // 576
  int xcd = bid & 7;
  int j = bid >> 3;                // 0..71
  int sb = xcd + ((j >= 36) ? 8 : 0);
  int p = (j >= 36) ? (j - 36) : j;
  int ti = 0;
  while (p >= 8 - ti) { p -= 8 - ti; ++ti; }
  int tj = ti + p;                 // ti <= tj
  int diag = (ti == tj);
  int s = sb >> 3, b = sb & 7;
  const float* x = s ? x1 : x0;
  const float* Axp = x + (size_t)b * NSEQ * NC + ti * 64;   // [n][c] slab, c-base ti*64
  const float* Bxp = x + (size_t)b * NSEQ * NC + tj * 64;
  int tid = threadIdx.x;
  int lane = tid & 63;
  int w = tid >> 6;
  int c4 = (tid & 15) * 4;         // c-group
  int n4 = (tid >> 4) * 4;         // n-group 0..60
  int wr = w & 1, wc = w >> 1;     // wave -> 32x32 quadrant
  int mrow = lane & 15;
  int kreg = lane >> 4;            // 0..3
  f4 z = {0.f, 0.f, 0.f, 0.f};
  f4 acc[2][2];
#pragma unroll
  for (int i = 0; i < 2; ++i)
#pragma unroll
    for (int jj = 0; jj < 2; ++jj) acc[i][jj] = z;

  f4 va[4], vb[4];
  auto load = [&](int n0) {
#pragma unroll
    for (int i = 0; i < 4; ++i)
      va[i] = *(const f4*)&Axp[(size_t)(n0 + n4 + i) * NC + c4];
    if (!diag) {
#pragma unroll
      for (int i = 0; i < 4; ++i)
        vb[i] = *(const f4*)&Bxp[(size_t)(n0 + n4 + i) * NC + c4];
    }
  };
  auto store = [&](int buf) {
#pragma unroll
    for (int ci = 0; ci < 4; ++ci) {
      int c = c4 + ci;
      int soff = c * 64 + ((((n4 >> 3) ^ (c & 7))) << 3) + (n4 & 7);
      u32x2 wa;
      wa[0] = cvtpk(va[0][ci], va[1][ci]);
      wa[1] = cvtpk(va[2][ci], va[3][ci]);
      *(u32x2*)&Ab[buf][soff] = wa;
      if (!diag) {
        u32x2 wb;
        wb[0] = cvtpk(vb[0][ci], vb[1][ci]);
        wb[1] = cvtpk(vb[2][ci], vb[3][ci]);
        *(u32x2*)&Bb[buf][soff] = wb;
      }
    }
  };
  auto comp = [&](int buf) {
    const short* Abuf = Ab[buf];
    const short* Bbuf = diag ? Ab[buf] : Bb[buf];
#pragma unroll
    for (int kk = 0; kk < 2; ++kk) {
      int gr = kk * 4 + kreg;
      bf8 a[2], bb[2];
#pragma unroll
      for (int i = 0; i < 2; ++i) {
        int ra = wr * 32 + i * 16 + mrow;
        a[i] = *(const bf8*)&Abuf[ra * 64 + ((gr ^ (ra & 7)) << 3)];
        int rb2 = wc * 32 + i * 16 + mrow;
        bb[i] = *(const bf8*)&Bbuf[rb2 * 64 + ((gr ^ (rb2 & 7)) << 3)];
      }
#pragma unroll
      for (int i = 0; i < 2; ++i)
#pragma unroll
        for (int jj = 0; jj < 2; ++jj)
          acc[i][jj] = __builtin_amdgcn_mfma_f32_16x16x32_bf16(a[i], bb[jj], acc[i][jj], 0, 0, 0);
    }
  };

  load(0);
  store(0);
  __syncthreads();
  int cur = 0;
  for (int it = 0; it < 64; ++it) {
    if (it < 63) load((it + 1) * 64);   // issue loads early: latency hides under MFMA
    comp(cur);
    if (it < 63) {
      store(cur ^ 1);                    // waitcnt+cvt+write after compute
      __syncthreads();
    }
    cur ^= 1;
  }

  float* Gp = G32 + (size_t)sb * NC * NC;
  int rb = ti * 64 + wr * 32 + (lane >> 4) * 4;
  int cb = tj * 64 + wc * 32 + (lane & 15);
#pragma unroll
  for (int i = 0; i < 2; ++i)
#pragma unroll
    for (int jj = 0; jj < 2; ++jj)
#pragma unroll
      for (int r = 0; r < 4; ++r)
        Gp[(size_t)(rb + i * 16 + r) * NC + cb + jj * 16] = acc[i][jj][r];
}

// K1b: mirror upper->full and pre-split SCALE*G into bf16 hi/lo.
__global__ __launch_bounds__(256) void k_sym(const float* __restrict__ G32,
                                             short* __restrict__ Gh,
                                             short* __restrict__ Gl) {
  __shared__ float t[64 * 65];
  int bid = blockIdx.x;           // 16 sb x 64 tiles
  int tile = bid & 63;
  int sb = bid >> 6;
  int ti = tile >> 3, tj = tile & 7;
  int tr = ti > tj;
  const float* src = G32 + (size_t)sb * 262144
                   + (tr ? ((size_t)(tj * 64) * 512 + ti * 64)
                         : ((size_t)(ti * 64) * 512 + tj * 64));
  int tid = threadIdx.x;
  int rr = tid >> 4;
  int c4 = (tid & 15) * 4;
#pragma unroll
  for (int p = 0; p < 4; ++p) {
    int r = p * 16 + rr;
    f4 v = *(const f4*)&src[(size_t)r * 512 + c4];
    if (tr) {
#pragma unroll
      for (int i = 0; i < 4; ++i) t[(c4 + i) * 65 + r] = v[i];
    } else {
#pragma unroll
      for (int i = 0; i < 4; ++i) t[r * 65 + c4 + i] = v[i];
    }
  }
  __syncthreads();
  size_t obase = (size_t)sb * 262144 + (size_t)(ti * 64) * 512 + tj * 64;
#pragma unroll
  for (int p = 0; p < 4; ++p) {
    int r = p * 16 + rr;
    bf4 vh, vl;
#pragma unroll
    for (int i = 0; i < 4; ++i) {
      float v = t[r * 65 + c4 + i] * 0.125f;
      short h = f2bf(v);
      vh[i] = h; vl[i] = f2bf(v - bf2f(h));
    }
    *(bf4*)&Gh[obase + (size_t)r * 512 + c4] = vh;
    *(bf4*)&Gl[obase + (size_t)r * 512 + c4] = vl;
  }
}

// K2: Ttf[sb][e][c] = sum_k Wv[k,e] * (SCALE*G[k,c]) in split-bf16 (hi/lo), f32 out.
__global__ __launch_bounds__(256) void k_t(const short* __restrict__ Wth,
                                           const short* __restrict__ Wtl,
                                           const short* __restrict__ Gh,
                                           const short* __restrict__ Gl,
                                           float* __restrict__ Ttf) {
  __shared__ short Ah[128 * 40];
  __shared__ short Al[128 * 40];
  __shared__ short Bh[128 * 40];
  __shared__ short Bl[128 * 40];
  int tid = threadIdx.x;
  int et = blockIdx.x & 3;
  int ct = blockIdx.x >> 2;
  int sb = blockIdx.y;
  int s = sb >> 3;
  const short* Avh = Wth + ((size_t)s * 1024 + 512 + (size_t)et * 128) * NC;
  const short* Avl = Wtl + ((size_t)s * 1024 + 512 + (size_t)et * 128) * NC;
  const short* Gph = Gh + (size_t)sb * 262144 + (size_t)(ct * 128) * 512;
  const short* Gpl = Gl + (size_t)sb * 262144 + (size_t)(ct * 128) * 512;
  int cc = tid >> 1;
  int kh = (tid & 1) * 16;
  int lane = tid & 63;
  int w = tid >> 6;
  int wm = (w & 1) * 64;
  int wn = (w >> 1) * 64;
  int mrow = lane & 15;
  int kcol = (lane >> 4) * 8;
  f4 z = {0.f, 0.f, 0.f, 0.f};
  f4 acc[4][4];
#pragma unroll
  for (int i = 0; i < 4; ++i)
#pragma unroll
    for (int j = 0; j < 4; ++j) acc[i][j] = z;

  for (int it = 0; it < 16; ++it) {
    int k0 = it * 32;
    __syncthreads();
    *(bf8*)&Ah[cc * 40 + kh]     = *(const bf8*)&Avh[(size_t)cc * NC + k0 + kh];
    *(bf8*)&Ah[cc * 40 + kh + 8] = *(const bf8*)&Avh[(size_t)cc * NC + k0 + kh + 8];
    *(bf8*)&Al[cc * 40 + kh]     = *(const bf8*)&Avl[(size_t)cc * NC + k0 + kh];
    *(bf8*)&Al[cc * 40 + kh + 8] = *(const bf8*)&Avl[(size_t)cc * NC + k0 + kh + 8];
    *(bf8*)&Bh[cc * 40 + kh]     = *(const bf8*)&Gph[(size_t)cc * 512 + k0 + kh];
    *(bf8*)&Bh[cc * 40 + kh + 8] = *(const bf8*)&Gph[(size_t)cc * 512 + k0 + kh + 8];
    *(bf8*)&Bl[cc * 40 + kh]     = *(const bf8*)&Gpl[(size_t)cc * 512 + k0 + kh];
    *(bf8*)&Bl[cc * 40 + kh + 8] = *(const bf8*)&Gpl[(size_t)cc * 512 + k0 + kh + 8];
    __syncthreads();
    bf8 ah[4], al[4], bh[4], bl[4];
#pragma unroll
    for (int i = 0; i < 4; ++i) {
      ah[i] = *(const bf8*)&Ah[(wm + i * 16 + mrow) * 40 + kcol];
      al[i] = *(const bf8*)&Al[(wm + i * 16 + mrow) * 40 + kcol];
      bh[i] = *(const bf8*)&Bh[(wn + i * 16 + mrow) * 40 + kcol];
      bl[i] = *(const bf8*)&Bl[(wn + i * 16 + mrow) * 40 + kcol];
    }
#pragma unroll
    for (int i = 0; i < 4; ++i)
#pragma unroll
      for (int j = 0; j < 4; ++j) {
        acc[i][j] = __builtin_amdgcn_mfma_f32_16x16x32_bf16(ah[i], bh[j], acc[i][j], 0, 0, 0);
        acc[i][j] = __builtin_amdgcn_mfma_f32_16x16x32_bf16(ah[i], bl[j], acc[i][j], 0, 0, 0);
        acc[i][j] = __builtin_amdgcn_mfma_f32_16x16x32_bf16(al[i], bh[j], acc[i][j], 0, 0, 0);
      }
  }
  float* Tp = Ttf + (size_t)sb * NC * NC;
  int rb = et * 128 + wm + (lane >> 4) * 4;
  int cb = ct * 128 + wn + (lane & 15);
#pragma unroll
  for (int i = 0; i < 4; ++i)
#pragma unroll
    for (int j = 0; j < 4; ++j)
#pragma unroll
      for (int r = 0; r < 4; ++r)
        Tp[(size_t)(rb + i * 16 + r) * NC + cb + j * 16] = acc[i][j][r];
}

// K3: per (sb,h): S[d,e] = sum_c Wk[c,d] * T[e,c] in split-bf16; softmax over d; ctxT[e][d] bf16.
__global__ __launch_bounds__(256) void k_ctx(const short* __restrict__ Wth,
                                             const short* __restrict__ Wtl,
                                             const float* __restrict__ Ttf,
                                             short* __restrict__ ctxT) {
  __shared__ short Ah[64 * 72];
  __shared__ short Al[64 * 72];
  __shared__ short Bh[64 * 72];
  __shared__ short Bl[64 * 72];
  __shared__ float Sf[64 * 68];
  int tid = threadIdx.x;
  int h = blockIdx.x & 7;
  int sb = blockIdx.x >> 3;
  int s = sb >> 3;
  const short* Akh = Wth + ((size_t)s * 1024 + (size_t)h * 64) * NC;
  const short* Akl = Wtl + ((size_t)s * 1024 + (size_t)h * 64) * NC;
  const float* Bt = Ttf + ((size_t)sb * NC + (size_t)h * 64) * NC;
  int cs = tid >> 3;
  int kg = (tid & 7) * 8;
  int lane = tid & 63;
  int w = tid >> 6;
  int mrow = lane & 15;
  int kcol = (lane >> 4) * 8;
  f4 z = {0.f, 0.f, 0.f, 0.f};
  f4 acc[4];
#pragma unroll
  for (int j = 0; j < 4; ++j) acc[j] = z;

  for (int it = 0; it < 8; ++it) {
    int k0 = it * 64;
    __syncthreads();
#pragma unroll
    for (int r = 0; r < 2; ++r) {
      int d = cs + r * 32;
      *(bf8*)&Ah[d * 72 + kg] = *(const bf8*)&Akh[(size_t)d * NC + k0 + kg];
      *(bf8*)&Al[d * 72 + kg] = *(const bf8*)&Akl[(size_t)d * NC + k0 + kg];
      f4 g0 = *(const f4*)&Bt[(size_t)d * NC + k0 + kg];
      f4 g1 = *(const f4*)&Bt[(size_t)d * NC + k0 + kg + 4];
      bf8 vh, vl;
#pragma unroll
      for (int i = 0; i < 4; ++i) {
        short hh = f2bf(g0[i]);
        vh[i] = hh; vl[i] = f2bf(g0[i] - bf2f(hh));
        hh = f2bf(g1[i]);
        vh[i + 4] = hh; vl[i + 4] = f2bf(g1[i] - bf2f(hh));
      }
      *(bf8*)&Bh[d * 72 + kg] = vh;
      *(bf8*)&Bl[d * 72 + kg] = vl;
    }
    __syncthreads();
#pragma unroll
    for (int kk = 0; kk < 2; ++kk) {
      bf8 ah = *(const bf8*)&Ah[(w * 16 + mrow) * 72 + kk * 32 + kcol];
      bf8 al = *(const bf8*)&Al[(w * 16 + mrow) * 72 + kk * 32 + kcol];
#pragma unroll
      for (int j = 0; j < 4; ++j) {
        bf8 bh = *(const bf8*)&Bh[(j * 16 + mrow) * 72 + kk * 32 + kcol];
        bf8 bl = *(const bf8*)&Bl[(j * 16 + mrow) * 72 + kk * 32 + kcol];
        acc[j] = __builtin_amdgcn_mfma_f32_16x16x32_bf16(ah, bh, acc[j], 0, 0, 0);
        acc[j] = __builtin_amdgcn_mfma_f32_16x16x32_bf16(ah, bl, acc[j], 0, 0, 0);
        acc[j] = __builtin_amdgcn_mfma_f32_16x16x32_bf16(al, bh, acc[j], 0, 0, 0);
      }
    }
  }
  __syncthreads();
#pragma unroll
  for (int j = 0; j < 4; ++j)
#pragma unroll
    for (int r = 0; r < 4; ++r)
      Sf[(w * 16 + (lane >> 4) * 4 + r) * 68 + j * 16 + (lane & 15)] = acc[j][r];
  __syncthreads();
  if (tid < 64) {
    int e = tid;
    float mx = -1e30f;
    for (int d = 0; d < 64; ++d) mx = fmaxf(mx, Sf[d * 68 + e]);
    float sum = 0.f;
    for (int d = 0; d < 64; ++d) {
      float ev = __expf(Sf[d * 68 + e] - mx);
      sum += ev;
      Sf[d * 68 + e] = ev;
    }
    float rs = 1.f / sum;
    short* cp = ctxT + (((size_t)sb * NH + h) * 64 + e) * 64;
    for (int d0 = 0; d0 < 64; d0 += 4) {
      bf4 ov;
      ov[0] = f2bf(Sf[(d0 + 0) * 68 + e] * rs);
      ov[1] = f2bf(Sf[(d0 + 1) * 68 + e] * rs);
      ov[2] = f2bf(Sf[(d0 + 2) * 68 + e] * rs);
      ov[3] = f2bf(Sf[(d0 + 3) * 68 + e] * rs);
      *(bf4*)&cp[d0] = ov;
    }
  }
}

// K4: o_so[b, n, h*64+e] = sum_d q_so[b,n,h*64+d] * ctx_{1-so}[d,e]
__global__ __launch_bounds__(256) void k_o(const float* __restrict__ x0,
                                           const float* __restrict__ x1,
                                           const short* __restrict__ ctxT,
                                           float* __restrict__ out) {
  __shared__ short Ab[128 * 72];
  __shared__ short Bb[64 * 72];
  int tid = threadIdx.x;
  int bx = blockIdx.x;            // [so 1][b 3][h 3][nt 5]
  int nt = bx & 31;
  int h = (bx >> 5) & 7;
  int b = (bx >> 8) & 7;
  int so = bx >> 11;
  const float* x = so ? x1 : x0;
  const short* cp = ctxT + (((size_t)(1 - so) * NB + b) * NH + h) * 64 * 64;
  {
    int e = tid >> 2;
    int dg = (tid & 3) * 16;
    *(bf8*)&Bb[e * 72 + dg] = *(const bf8*)&cp[e * 64 + dg];
    *(bf8*)&Bb[e * 72 + dg + 8] = *(const bf8*)&cp[e * 64 + dg + 8];
  }
  const float* xp = x + ((size_t)b * NSEQ + (size_t)nt * 128) * NC + h * 64;
  {
    int n = tid >> 1;
    int dh = (tid & 1) * 32;
    const float* row = xp + (size_t)n * NC + dh;
#pragma unroll
    for (int q = 0; q < 4; ++q) {
      f4 v0 = *(const f4*)&row[q * 8];
      f4 v1 = *(const f4*)&row[q * 8 + 4];
      u32x4 pw;
      pw[0] = cvtpk(v0[0], v0[1]);
      pw[1] = cvtpk(v0[2], v0[3]);
      pw[2] = cvtpk(v1[0], v1[1]);
      pw[3] = cvtpk(v1[2], v1[3]);
      *(u32x4*)&Ab[n * 72 + dh + q * 8] = pw;
    }
  }
  __syncthreads();
  int lane = tid & 63;
  int w = tid >> 6;
  int mrow = lane & 15;
  int kcol = (lane >> 4) * 8;
  f4 z = {0.f, 0.f, 0.f, 0.f};
  f4 acc[2][4];
#pragma unroll
  for (int i = 0; i < 2; ++i)
#pragma unroll
    for (int j = 0; j < 4; ++j) acc[i][j] = z;
#pragma unroll
  for (int kk = 0; kk < 2; ++kk) {
    bf8 a0 = *(const bf8*)&Ab[(w * 32 + mrow) * 72 + kk * 32 + kcol];
    bf8 a1 = *(const bf8*)&Ab[(w * 32 + 16 + mrow) * 72 + kk * 32 + kcol];
#pragma unroll
    for (int j = 0; j < 4; ++j) {
      bf8 bv = *(const bf8*)&Bb[(j * 16 + mrow) * 72 + kk * 32 + kcol];
      acc[0][j] = __builtin_amdgcn_mfma_f32_16x16x32_bf16(a0, bv, acc[0][j], 0, 0, 0);
      acc[1][j] = __builtin_amdgcn_mfma_f32_16x16x32_bf16(a1, bv, acc[1][j], 0, 0, 0);
    }
  }
  float* op = out + (size_t)so * ((size_t)NB * NSEQ * NC)
            + ((size_t)b * NSEQ + (size_t)nt * 128) * NC + h * 64;
#pragma unroll
  for (int i = 0; i < 2; ++i)
#pragma unroll
    for (int j = 0; j < 4; ++j)
#pragma unroll
      for (int r = 0; r < 4; ++r)
        op[(size_t)(w * 32 + i * 16 + (lane >> 4) * 4 + r) * NC + j * 16 + (lane & 15)] = acc[i][j][r];
}

extern "C" void kernel_launch(void* const* d_in, const int* in_sizes, int n_in,
                              void* d_out, int out_size, void* d_ws, size_t ws_size,
                              hipStream_t stream) {
  const float* x1 = (const float*)d_in[0];
  const float* x2 = (const float*)d_in[1];
  const float* W1 = (const float*)d_in[2];
  const float* W2 = (const float*)d_in[3];
  float* out = (float*)d_out;
  char* ws = (char*)d_ws;
  float* Ttf  = (float*)ws;                   // 16,777,216 B
  short* Gh   = (short*)(ws + 16777216);      //  8,388,608 B
  short* Gl   = (short*)(ws + 25165824);      //  8,388,608 B
  short* Wth  = (short*)(ws + 67108864);      //  2,097,152 B
  short* Wtl  = (short*)(ws + 69206016);      //  2,097,152 B
  float* G32  = (float*)(ws + 71303168);      // 16,777,216 B
  short* ctxT = (short*)(ws + 88080384);      //  1,048,576 B

  hipLaunchKernelGGL(k_wt,   dim3(256),    dim3(256), 0, stream, W1, W2, Wth, Wtl);
  hipLaunchKernelGGL(k_gram, dim3(576),    dim3(256), 0, stream, x1, x2, G32);
  hipLaunchKernelGGL(k_sym,  dim3(1024),   dim3(256), 0, stream, G32, Gh, Gl);
  hipLaunchKernelGGL(k_t,    dim3(16, 16), dim3(256), 0, stream, Wth, Wtl, Gh, Gl, Ttf);
  hipLaunchKernelGGL(k_ctx,  dim3(128),    dim3(256), 0, stream, Wth, Wtl, Ttf, ctxT);
  hipLaunchKernelGGL(k_o,    dim3(4096),   dim3(256), 0, stream, x1, x2, ctxT, out);
}

// Round 6
// 166.584 us; speedup vs baseline: 1.3326x; 1.3326x over previous
//
#include <hip/hip_runtime.h>
#include <stdint.h>
#include <stddef.h>

#define NB 8
#define NSEQ 4096
#define NC 512
#define NH 8
#define SWZ(c) ((((c) >> 2) ^ (c)) & 7)

typedef __attribute__((ext_vector_type(4))) float f4;
typedef __attribute__((ext_vector_type(8))) short bf8;
typedef __attribute__((ext_vector_type(4))) short bf4;
typedef __attribute__((ext_vector_type(2))) unsigned int u32x2;
typedef __attribute__((ext_vector_type(4))) unsigned int u32x4;

__device__ __forceinline__ short f2bf(float f) {
  union { float f; unsigned int u; } v; v.f = f;
  unsigned int u = v.u + 0x7FFFu + ((v.u >> 16) & 1u);
  return (short)(u >> 16);
}
__device__ __forceinline__ float bf2f(short h) {
  union { unsigned int u; float f; } v;
  v.u = ((unsigned int)(unsigned short)h) << 16;
  return v.f;
}
__device__ __forceinline__ unsigned int cvtpk(float a, float b) {
  unsigned int r;
  asm("v_cvt_pk_bf16_f32 %0, %1, %2" : "=v"(r) : "v"(a), "v"(b));
  return r;
}

// K0a: Wth/Wtl[s][o][c] = split(W_s[c][o]) via 64x64 LDS transpose (coalesced both sides).
__global__ __launch_bounds__(256) void k_wt(const float* __restrict__ W0,
                                            const float* __restrict__ W1,
                                            short* __restrict__ Wth,
                                            short* __restrict__ Wtl) {
  __shared__ float t[64 * 65];
  int bid = blockIdx.x;           // [s 1][ct 3][ot 4] = 256
  int ot = bid & 15;
  int ct = (bid >> 4) & 7;
  int s = bid >> 7;
  const float* W = s ? W1 : W0;
  const float* src = W + (size_t)(ct * 64) * 1024 + ot * 64;   // [c][o]
  int tid = threadIdx.x;
  int rr = tid >> 4, c4 = (tid & 15) * 4;
#pragma unroll
  for (int p = 0; p < 4; ++p) {
    int c = p * 16 + rr;
    f4 v = *(const f4*)&src[(size_t)c * 1024 + c4];
#pragma unroll
    for (int i = 0; i < 4; ++i) t[(c4 + i) * 65 + c] = v[i];   // t[o][c]
  }
  __syncthreads();
  size_t obase = (size_t)s * 524288 + (size_t)(ot * 64) * 512 + ct * 64;
#pragma unroll
  for (int p = 0; p < 4; ++p) {
    int o = p * 16 + rr;
    bf4 vh, vl;
#pragma unroll
    for (int i = 0; i < 4; ++i) {
      float v = t[o * 65 + c4 + i];
      short h = f2bf(v);
      vh[i] = h; vl[i] = f2bf(v - bf2f(h));
    }
    *(bf4*)&Wth[obase + (size_t)o * 512 + c4] = vh;
    *(bf4*)&Wtl[obase + (size_t)o * 512 + c4] = vl;
  }
}

// K1: G32[kh][sb] upper 64x64 tile-pairs = X^T X over n-half kh, reading f32 x directly.
// Split-n=2 (no atomics; k_sym sums the halves). Single 16KB LDS buffer; regs hold
// tile t+1 during comp(t); sched_barrier pins the early load issue.
// LDS layout: [c][n] bf16, granule slot = g ^ SWZ(c)  (conflict-free write AND read).
__global__ __launch_bounds__(256) void k_gram(const float* __restrict__ x0,
                                              const float* __restrict__ x1,
                                              float* __restrict__ G32a,
                                              float* __restrict__ G32b) {
  __shared__ short Ab[64 * 64];
  __shared__ short Bb[64 * 64];
  int bid = blockIdx.x;            // 1152
  int xcd = bid & 7;
  int j = bid >> 3;                // 0..143
  int kh = j >= 72;
  int jj = j - kh * 72;            // 0..71
  int sb = xcd + ((jj >= 36) ? 8 : 0);
  int p = (jj >= 36) ? (jj - 36) : jj;
  int ti = 0;
  while (p >= 8 - ti) { p -= 8 - ti; ++ti; }
  int tj = ti + p;                 // ti <= tj
  int diag = (ti == tj);
  int s = sb >> 3, b = sb & 7;
  const float* x = s ? x1 : x0;
  const float* Axp = x + (size_t)b * NSEQ * NC + (size_t)kh * 2048 * NC + ti * 64;
  const float* Bxp = x + (size_t)b * NSEQ * NC + (size_t)kh * 2048 * NC + tj * 64;
  int tid = threadIdx.x;
  int lane = tid & 63;
  int w = tid >> 6;
  int c4 = (tid & 15) * 4;         // c-group 0..60
  int n4 = (tid >> 4) * 4;         // n-group 0..60
  int g = n4 >> 3;                 // granule of this thread's 4 n's
  int nlo = n4 & 7;                // 0 or 4
  int wr = w & 1, wc = w >> 1;     // wave -> 32x32 quadrant
  int mrow = lane & 15;
  int kreg = lane >> 4;            // 0..3
  f4 z = {0.f, 0.f, 0.f, 0.f};
  f4 acc[2][2];
#pragma unroll
  for (int i = 0; i < 2; ++i)
#pragma unroll
    for (int jq = 0; jq < 2; ++jq) acc[i][jq] = z;

  f4 va[4], vb[4];
  auto load = [&](int n0) {
#pragma unroll
    for (int i = 0; i < 4; ++i)
      va[i] = *(const f4*)&Axp[(size_t)(n0 + n4 + i) * NC + c4];
    if (!diag) {
#pragma unroll
      for (int i = 0; i < 4; ++i)
        vb[i] = *(const f4*)&Bxp[(size_t)(n0 + n4 + i) * NC + c4];
    }
  };
  auto store = [&]() {
#pragma unroll
    for (int ci = 0; ci < 4; ++ci) {
      int c = c4 + ci;
      int soff = c * 64 + ((g ^ SWZ(c)) << 3) + nlo;
      u32x2 wa;
      wa[0] = cvtpk(va[0][ci], va[1][ci]);
      wa[1] = cvtpk(va[2][ci], va[3][ci]);
      *(u32x2*)&Ab[soff] = wa;
      if (!diag) {
        u32x2 wb;
        wb[0] = cvtpk(vb[0][ci], vb[1][ci]);
        wb[1] = cvtpk(vb[2][ci], vb[3][ci]);
        *(u32x2*)&Bb[soff] = wb;
      }
    }
  };
  auto comp = [&]() {
    const short* Bbuf = diag ? Ab : Bb;
#pragma unroll
    for (int kk = 0; kk < 2; ++kk) {
      int gr = kk * 4 + kreg;
      bf8 a[2], bb[2];
#pragma unroll
      for (int i = 0; i < 2; ++i) {
        int ra = wr * 32 + i * 16 + mrow;
        a[i] = *(const bf8*)&Ab[ra * 64 + ((gr ^ SWZ(ra)) << 3)];
        int rb2 = wc * 32 + i * 16 + mrow;
        bb[i] = *(const bf8*)&Bbuf[rb2 * 64 + ((gr ^ SWZ(rb2)) << 3)];
      }
#pragma unroll
      for (int i = 0; i < 2; ++i)
#pragma unroll
        for (int jq = 0; jq < 2; ++jq)
          acc[i][jq] = __builtin_amdgcn_mfma_f32_16x16x32_bf16(a[i], bb[jq], acc[i][jq], 0, 0, 0);
    }
  };

  load(0);
  for (int it = 0; it < 32; ++it) {
    store();                               // waits loads, cvt_pk, conflict-free ds_write
    __syncthreads();                       // tile visible to all waves
    if (it < 31) load((it + 1) * 64);      // issue next loads: fly during comp
    __builtin_amdgcn_sched_barrier(0);     // pin load issue above the MFMA cluster
    comp();
    __syncthreads();                       // reads done before next store
  }

  float* Gp = (kh ? G32b : G32a) + (size_t)sb * NC * NC;
  int rb = ti * 64 + wr * 32 + (lane >> 4) * 4;
  int cb = tj * 64 + wc * 32 + (lane & 15);
#pragma unroll
  for (int i = 0; i < 2; ++i)
#pragma unroll
    for (int jq = 0; jq < 2; ++jq)
#pragma unroll
      for (int r = 0; r < 4; ++r)
        Gp[(size_t)(rb + i * 16 + r) * NC + cb + jq * 16] = acc[i][jq][r];
}

// K1b: sum n-halves, mirror upper->full, pre-split SCALE*G into bf16 hi/lo.
__global__ __launch_bounds__(256) void k_sym(const float* __restrict__ G32a,
                                             const float* __restrict__ G32b,
                                             short* __restrict__ Gh,
                                             short* __restrict__ Gl) {
  __shared__ float t[64 * 65];
  int bid = blockIdx.x;           // 16 sb x 64 tiles
  int tile = bid & 63;
  int sb = bid >> 6;
  int ti = tile >> 3, tj = tile & 7;
  int tr = ti > tj;
  size_t soff = (size_t)sb * 262144
              + (tr ? ((size_t)(tj * 64) * 512 + ti * 64)
                    : ((size_t)(ti * 64) * 512 + tj * 64));
  const float* srcA = G32a + soff;
  const float* srcB = G32b + soff;
  int tid = threadIdx.x;
  int rr = tid >> 4;
  int c4 = (tid & 15) * 4;
#pragma unroll
  for (int p = 0; p < 4; ++p) {
    int r = p * 16 + rr;
    f4 v = *(const f4*)&srcA[(size_t)r * 512 + c4];
    f4 v2 = *(const f4*)&srcB[(size_t)r * 512 + c4];
    v += v2;
    if (tr) {
#pragma unroll
      for (int i = 0; i < 4; ++i) t[(c4 + i) * 65 + r] = v[i];
    } else {
#pragma unroll
      for (int i = 0; i < 4; ++i) t[r * 65 + c4 + i] = v[i];
    }
  }
  __syncthreads();
  size_t obase = (size_t)sb * 262144 + (size_t)(ti * 64) * 512 + tj * 64;
#pragma unroll
  for (int p = 0; p < 4; ++p) {
    int r = p * 16 + rr;
    bf4 vh, vl;
#pragma unroll
    for (int i = 0; i < 4; ++i) {
      float v = t[r * 65 + c4 + i] * 0.125f;
      short h = f2bf(v);
      vh[i] = h; vl[i] = f2bf(v - bf2f(h));
    }
    *(bf4*)&Gh[obase + (size_t)r * 512 + c4] = vh;
    *(bf4*)&Gl[obase + (size_t)r * 512 + c4] = vl;
  }
}

// K2: Ttf[sb][e][c] = sum_k Wv[k,e] * (SCALE*G[k,c]) in split-bf16 (hi/lo), f32 out.
__global__ __launch_bounds__(256) void k_t(const short* __restrict__ Wth,
                                           const short* __restrict__ Wtl,
                                           const short* __restrict__ Gh,
                                           const short* __restrict__ Gl,
                                           float* __restrict__ Ttf) {
  __shared__ short Ah[128 * 40];
  __shared__ short Al[128 * 40];
  __shared__ short Bh[128 * 40];
  __shared__ short Bl[128 * 40];
  int tid = threadIdx.x;
  int et = blockIdx.x & 3;
  int ct = blockIdx.x >> 2;
  int sb = blockIdx.y;
  int s = sb >> 3;
  const short* Avh = Wth + ((size_t)s * 1024 + 512 + (size_t)et * 128) * NC;
  const short* Avl = Wtl + ((size_t)s * 1024 + 512 + (size_t)et * 128) * NC;
  const short* Gph = Gh + (size_t)sb * 262144 + (size_t)(ct * 128) * 512;
  const short* Gpl = Gl + (size_t)sb * 262144 + (size_t)(ct * 128) * 512;
  int cc = tid >> 1;
  int kh = (tid & 1) * 16;
  int lane = tid & 63;
  int w = tid >> 6;
  int wm = (w & 1) * 64;
  int wn = (w >> 1) * 64;
  int mrow = lane & 15;
  int kcol = (lane >> 4) * 8;
  f4 z = {0.f, 0.f, 0.f, 0.f};
  f4 acc[4][4];
#pragma unroll
  for (int i = 0; i < 4; ++i)
#pragma unroll
    for (int j = 0; j < 4; ++j) acc[i][j] = z;

  for (int it = 0; it < 16; ++it) {
    int k0 = it * 32;
    __syncthreads();
    *(bf8*)&Ah[cc * 40 + kh]     = *(const bf8*)&Avh[(size_t)cc * NC + k0 + kh];
    *(bf8*)&Ah[cc * 40 + kh + 8] = *(const bf8*)&Avh[(size_t)cc * NC + k0 + kh + 8];
    *(bf8*)&Al[cc * 40 + kh]     = *(const bf8*)&Avl[(size_t)cc * NC + k0 + kh];
    *(bf8*)&Al[cc * 40 + kh + 8] = *(const bf8*)&Avl[(size_t)cc * NC + k0 + kh + 8];
    *(bf8*)&Bh[cc * 40 + kh]     = *(const bf8*)&Gph[(size_t)cc * 512 + k0 + kh];
    *(bf8*)&Bh[cc * 40 + kh + 8] = *(const bf8*)&Gph[(size_t)cc * 512 + k0 + kh + 8];
    *(bf8*)&Bl[cc * 40 + kh]     = *(const bf8*)&Gpl[(size_t)cc * 512 + k0 + kh];
    *(bf8*)&Bl[cc * 40 + kh + 8] = *(const bf8*)&Gpl[(size_t)cc * 512 + k0 + kh + 8];
    __syncthreads();
    bf8 ah[4], al[4], bh[4], bl[4];
#pragma unroll
    for (int i = 0; i < 4; ++i) {
      ah[i] = *(const bf8*)&Ah[(wm + i * 16 + mrow) * 40 + kcol];
      al[i] = *(const bf8*)&Al[(wm + i * 16 + mrow) * 40 + kcol];
      bh[i] = *(const bf8*)&Bh[(wn + i * 16 + mrow) * 40 + kcol];
      bl[i] = *(const bf8*)&Bl[(wn + i * 16 + mrow) * 40 + kcol];
    }
#pragma unroll
    for (int i = 0; i < 4; ++i)
#pragma unroll
      for (int j = 0; j < 4; ++j) {
        acc[i][j] = __builtin_amdgcn_mfma_f32_16x16x32_bf16(ah[i], bh[j], acc[i][j], 0, 0, 0);
        acc[i][j] = __builtin_amdgcn_mfma_f32_16x16x32_bf16(ah[i], bl[j], acc[i][j], 0, 0, 0);
        acc[i][j] = __builtin_amdgcn_mfma_f32_16x16x32_bf16(al[i], bh[j], acc[i][j], 0, 0, 0);
      }
  }
  float* Tp = Ttf + (size_t)sb * NC * NC;
  int rb = et * 128 + wm + (lane >> 4) * 4;
  int cb = ct * 128 + wn + (lane & 15);
#pragma unroll
  for (int i = 0; i < 4; ++i)
#pragma unroll
    for (int j = 0; j < 4; ++j)
#pragma unroll
      for (int r = 0; r < 4; ++r)
        Tp[(size_t)(rb + i * 16 + r) * NC + cb + j * 16] = acc[i][j][r];
}

// K3: per (sb,h): S[d,e] = sum_c Wk[c,d] * T[e,c] in split-bf16; softmax over d; ctxT[e][d] bf16.
__global__ __launch_bounds__(256) void k_ctx(const short* __restrict__ Wth,
                                             const short* __restrict__ Wtl,
                                             const float* __restrict__ Ttf,
                                             short* __restrict__ ctxT) {
  __shared__ short Ah[64 * 72];
  __shared__ short Al[64 * 72];
  __shared__ short Bh[64 * 72];
  __shared__ short Bl[64 * 72];
  __shared__ float Sf[64 * 68];
  int tid = threadIdx.x;
  int h = blockIdx.x & 7;
  int sb = blockIdx.x >> 3;
  int s = sb >> 3;
  const short* Akh = Wth + ((size_t)s * 1024 + (size_t)h * 64) * NC;
  const short* Akl = Wtl + ((size_t)s * 1024 + (size_t)h * 64) * NC;
  const float* Bt = Ttf + ((size_t)sb * NC + (size_t)h * 64) * NC;
  int cs = tid >> 3;
  int kg = (tid & 7) * 8;
  int lane = tid & 63;
  int w = tid >> 6;
  int mrow = lane & 15;
  int kcol = (lane >> 4) * 8;
  f4 z = {0.f, 0.f, 0.f, 0.f};
  f4 acc[4];
#pragma unroll
  for (int j = 0; j < 4; ++j) acc[j] = z;

  for (int it = 0; it < 8; ++it) {
    int k0 = it * 64;
    __syncthreads();
#pragma unroll
    for (int r = 0; r < 2; ++r) {
      int d = cs + r * 32;
      *(bf8*)&Ah[d * 72 + kg] = *(const bf8*)&Akh[(size_t)d * NC + k0 + kg];
      *(bf8*)&Al[d * 72 + kg] = *(const bf8*)&Akl[(size_t)d * NC + k0 + kg];
      f4 g0 = *(const f4*)&Bt[(size_t)d * NC + k0 + kg];
      f4 g1 = *(const f4*)&Bt[(size_t)d * NC + k0 + kg + 4];
      bf8 vh, vl;
#pragma unroll
      for (int i = 0; i < 4; ++i) {
        short hh = f2bf(g0[i]);
        vh[i] = hh; vl[i] = f2bf(g0[i] - bf2f(hh));
        hh = f2bf(g1[i]);
        vh[i + 4] = hh; vl[i + 4] = f2bf(g1[i] - bf2f(hh));
      }
      *(bf8*)&Bh[d * 72 + kg] = vh;
      *(bf8*)&Bl[d * 72 + kg] = vl;
    }
    __syncthreads();
#pragma unroll
    for (int kk = 0; kk < 2; ++kk) {
      bf8 ah = *(const bf8*)&Ah[(w * 16 + mrow) * 72 + kk * 32 + kcol];
      bf8 al = *(const bf8*)&Al[(w * 16 + mrow) * 72 + kk * 32 + kcol];
#pragma unroll
      for (int j = 0; j < 4; ++j) {
        bf8 bh = *(const bf8*)&Bh[(j * 16 + mrow) * 72 + kk * 32 + kcol];
        bf8 bl = *(const bf8*)&Bl[(j * 16 + mrow) * 72 + kk * 32 + kcol];
        acc[j] = __builtin_amdgcn_mfma_f32_16x16x32_bf16(ah, bh, acc[j], 0, 0, 0);
        acc[j] = __builtin_amdgcn_mfma_f32_16x16x32_bf16(ah, bl, acc[j], 0, 0, 0);
        acc[j] = __builtin_amdgcn_mfma_f32_16x16x32_bf16(al, bh, acc[j], 0, 0, 0);
      }
    }
  }
  __syncthreads();
#pragma unroll
  for (int j = 0; j < 4; ++j)
#pragma unroll
    for (int r = 0; r < 4; ++r)
      Sf[(w * 16 + (lane >> 4) * 4 + r) * 68 + j * 16 + (lane & 15)] = acc[j][r];
  __syncthreads();
  if (tid < 64) {
    int e = tid;
    float mx = -1e30f;
    for (int d = 0; d < 64; ++d) mx = fmaxf(mx, Sf[d * 68 + e]);
    float sum = 0.f;
    for (int d = 0; d < 64; ++d) {
      float ev = __expf(Sf[d * 68 + e] - mx);
      sum += ev;
      Sf[d * 68 + e] = ev;
    }
    float rs = 1.f / sum;
    short* cp = ctxT + (((size_t)sb * NH + h) * 64 + e) * 64;
    for (int d0 = 0; d0 < 64; d0 += 4) {
      bf4 ov;
      ov[0] = f2bf(Sf[(d0 + 0) * 68 + e] * rs);
      ov[1] = f2bf(Sf[(d0 + 1) * 68 + e] * rs);
      ov[2] = f2bf(Sf[(d0 + 2) * 68 + e] * rs);
      ov[3] = f2bf(Sf[(d0 + 3) * 68 + e] * rs);
      *(bf4*)&cp[d0] = ov;
    }
  }
}

// K4: o_so[b, n, h*64+e] = sum_d q_so[b,n,h*64+d] * ctx_{1-so}[d,e]
__global__ __launch_bounds__(256) void k_o(const float* __restrict__ x0,
                                           const float* __restrict__ x1,
                                           const short* __restrict__ ctxT,
                                           float* __restrict__ out) {
  __shared__ short Ab[128 * 72];
  __shared__ short Bb[64 * 72];
  int tid = threadIdx.x;
  int bx = blockIdx.x;            // [so 1][b 3][h 3][nt 5]
  int nt = bx & 31;
  int h = (bx >> 5) & 7;
  int b = (bx >> 8) & 7;
  int so = bx >> 11;
  const float* x = so ? x1 : x0;
  const short* cp = ctxT + (((size_t)(1 - so) * NB + b) * NH + h) * 64 * 64;
  {
    int e = tid >> 2;
    int dg = (tid & 3) * 16;
    *(bf8*)&Bb[e * 72 + dg] = *(const bf8*)&cp[e * 64 + dg];
    *(bf8*)&Bb[e * 72 + dg + 8] = *(const bf8*)&cp[e * 64 + dg + 8];
  }
  const float* xp = x + ((size_t)b * NSEQ + (size_t)nt * 128) * NC + h * 64;
  {
    int n = tid >> 1;
    int dh = (tid & 1) * 32;
    const float* row = xp + (size_t)n * NC + dh;
#pragma unroll
    for (int q = 0; q < 4; ++q) {
      f4 v0 = *(const f4*)&row[q * 8];
      f4 v1 = *(const f4*)&row[q * 8 + 4];
      u32x4 pw;
      pw[0] = cvtpk(v0[0], v0[1]);
      pw[1] = cvtpk(v0[2], v0[3]);
      pw[2] = cvtpk(v1[0], v1[1]);
      pw[3] = cvtpk(v1[2], v1[3]);
      *(u32x4*)&Ab[n * 72 + dh + q * 8] = pw;
    }
  }
  __syncthreads();
  int lane = tid & 63;
  int w = tid >> 6;
  int mrow = lane & 15;
  int kcol = (lane >> 4) * 8;
  f4 z = {0.f, 0.f, 0.f, 0.f};
  f4 acc[2][4];
#pragma unroll
  for (int i = 0; i < 2; ++i)
#pragma unroll
    for (int j = 0; j < 4; ++j) acc[i][j] = z;
#pragma unroll
  for (int kk = 0; kk < 2; ++kk) {
    bf8 a0 = *(const bf8*)&Ab[(w * 32 + mrow) * 72 + kk * 32 + kcol];
    bf8 a1 = *(const bf8*)&Ab[(w * 32 + 16 + mrow) * 72 + kk * 32 + kcol];
#pragma unroll
    for (int j = 0; j < 4; ++j) {
      bf8 bv = *(const bf8*)&Bb[(j * 16 + mrow) * 72 + kk * 32 + kcol];
      acc[0][j] = __builtin_amdgcn_mfma_f32_16x16x32_bf16(a0, bv, acc[0][j], 0, 0, 0);
      acc[1][j] = __builtin_amdgcn_mfma_f32_16x16x32_bf16(a1, bv, acc[1][j], 0, 0, 0);
    }
  }
  float* op = out + (size_t)so * ((size_t)NB * NSEQ * NC)
            + ((size_t)b * NSEQ + (size_t)nt * 128) * NC + h * 64;
#pragma unroll
  for (int i = 0; i < 2; ++i)
#pragma unroll
    for (int j = 0; j < 4; ++j)
#pragma unroll
      for (int r = 0; r < 4; ++r)
        op[(size_t)(w * 32 + i * 16 + (lane >> 4) * 4 + r) * NC + j * 16 + (lane & 15)] = acc[i][j][r];
}

extern "C" void kernel_launch(void* const* d_in, const int* in_sizes, int n_in,
                              void* d_out, int out_size, void* d_ws, size_t ws_size,
                              hipStream_t stream) {
  const float* x1 = (const float*)d_in[0];
  const float* x2 = (const float*)d_in[1];
  const float* W1 = (const float*)d_in[2];
  const float* W2 = (const float*)d_in[3];
  float* out = (float*)d_out;
  char* ws = (char*)d_ws;
  float* Ttf  = (float*)ws;                   // 16,777,216 B
  short* Gh   = (short*)(ws + 16777216);      //  8,388,608 B
  short* Gl   = (short*)(ws + 25165824);      //  8,388,608 B
  float* G32a = (float*)(ws + 33554432);      // 16,777,216 B
  float* G32b = (float*)(ws + 50331648);      // 16,777,216 B
  short* Wth  = (short*)(ws + 67108864);      //  2,097,152 B
  short* Wtl  = (short*)(ws + 69206016);      //  2,097,152 B
  short* ctxT = (short*)(ws + 71303168);      //  1,048,576 B

  hipLaunchKernelGGL(k_wt,   dim3(256),    dim3(256), 0, stream, W1, W2, Wth, Wtl);
  hipLaunchKernelGGL(k_gram, dim3(1152),   dim3(256), 0, stream, x1, x2, G32a, G32b);
  hipLaunchKernelGGL(k_sym,  dim3(1024),   dim3(256), 0, stream, G32a, G32b, Gh, Gl);
  hipLaunchKernelGGL(k_t,    dim3(16, 16), dim3(256), 0, stream, Wth, Wtl, Gh, Gl, Ttf);
  hipLaunchKernelGGL(k_ctx,  dim3(128),    dim3(256), 0, stream, Wth, Wtl, Ttf, ctxT);
  hipLaunchKernelGGL(k_o,    dim3(4096),   dim3(256), 0, stream, x1, x2, ctxT, out);
}